// Round 1
// 602.388 us; speedup vs baseline: 1.1634x; 1.1634x over previous
//
#include <hip/hip_runtime.h>
#include <hip/hip_bf16.h>

#define NN 8192
#define CFEAT 512
#define NCLS 40
#define NPAD 48
#define INDIM 672
#define HIDD 1024

typedef __attribute__((ext_vector_type(8))) short bf16x8;
typedef __attribute__((ext_vector_type(4))) float f32x4;

#define A_SCALE 1048576.0f        // 2^20
#define A_INV_SCALE 9.5367431640625e-07f  // 2^-20

__device__ inline unsigned short f2b(float f) {
  union { __hip_bfloat16 b; unsigned short u; } cv;
  cv.b = __float2bfloat16(f);
  return cv.u;
}

__device__ inline unsigned char f2fp8(float f) {
  int pk = __builtin_amdgcn_cvt_pk_fp8_f32(f, 0.f, 0, false);
  return (unsigned char)(pk & 0xff);
}

// Interleaved fp8 matrix layout so hop_kernel wave-loads are CONTIGUOUS 512B:
// granule (row r, 8 cols starting 8*G) lives at byte offset
//   (r>>4)*131072 + (G>>7)*16384 + ((G>>2)&31)*512 + (G&3)*128 + (r&15)*8
// Hop lane (l15,kg) of wave w at iter t then reads base + w*16384 + t*512 + lane*8.
__device__ inline size_t ilv_off(int r, int G) {
  return (size_t)(r >> 4) * 131072 + (size_t)(G >> 7) * 16384 +
         (size_t)((G >> 2) & 31) * 512 + (size_t)(G & 3) * 128 + (size_t)(r & 15) * 8;
}

// ---------------------------------------------------------------------------
// K1: A8[i][k] = fp8_e4m3( 2^20 * sigmoid(adj[i][k]) / (rowsum + 1e-8) )
// one block per row; sigmoid row kept in 32 VGPRs. Writes INTERLEAVED layout
// (4B pieces at 128B stride; the 16 rows of a group run concurrently -> L2
// merges lines before eviction, HBM write bytes unchanged).
// sigmoid via v_rcp_f32 (approx ok: result is quantized to e4m3 anyway).
// ---------------------------------------------------------------------------
__global__ __launch_bounds__(256) void normalize_kernel(const float* __restrict__ adj,
                                                        unsigned char* __restrict__ A8) {
  __shared__ float wsum[4];
  const int t = threadIdx.x;
  const size_t i = blockIdx.x;
  const float4* src = (const float4*)(adj + i * NN);
  float4 v[8];
  float sum = 0.f;
#pragma unroll
  for (int it = 0; it < 8; ++it) {
    float4 x = src[it * 256 + t];
    float s0 = __builtin_amdgcn_rcpf(1.f + __expf(-x.x));
    float s1 = __builtin_amdgcn_rcpf(1.f + __expf(-x.y));
    float s2 = __builtin_amdgcn_rcpf(1.f + __expf(-x.z));
    float s3 = __builtin_amdgcn_rcpf(1.f + __expf(-x.w));
    v[it] = make_float4(s0, s1, s2, s3);
    sum += (s0 + s1) + (s2 + s3);
  }
#pragma unroll
  for (int m = 1; m < 64; m <<= 1) sum += __shfl_xor(sum, m);
  if ((t & 63) == 0) wsum[t >> 6] = sum;
  __syncthreads();
  const float dinv = A_SCALE / (wsum[0] + wsum[1] + wsum[2] + wsum[3] + 1e-8f);
  // thread t, iter it covers k = it*1024 + t*4 (4 bytes within granule G)
  // offset = (i>>4)*131072 + it*16384 + (t>>3)*512 + ((t>>1)&3)*128 + (i&15)*8 + (t&1)*4
  unsigned char* base = A8 + (size_t)(i >> 4) * 131072 + (size_t)(t >> 3) * 512 +
                        (size_t)((t >> 1) & 3) * 128 + (size_t)(i & 15) * 8 + (size_t)(t & 1) * 4;
#pragma unroll
  for (int it = 0; it < 8; ++it) {
    int lo = __builtin_amdgcn_cvt_pk_fp8_f32(v[it].x * dinv, v[it].y * dinv, 0, false);
    int pk = __builtin_amdgcn_cvt_pk_fp8_f32(v[it].z * dinv, v[it].w * dinv, lo, true);
    *(unsigned int*)(base + (size_t)it * 16384) = (unsigned int)pk;
  }
}

// ---------------------------------------------------------------------------
// prep: X -> combined[:, :512] bf16 ; onehot -> curT0 [48 x 8192] fp8
// (interleaved layout); W1 -> W1T bf16 ; W2 -> W2T bf16. pad rows of curT/W2T
// stay poisoned (finite or NaN is fine: per-lane isolated + masked downstream).
// ---------------------------------------------------------------------------
__global__ __launch_bounds__(256) void prep_kernel(const float* __restrict__ X,
                                                   const float* __restrict__ onehot,
                                                   const float* __restrict__ W1,
                                                   const float* __restrict__ W2,
                                                   unsigned short* __restrict__ comb,
                                                   unsigned char* __restrict__ curT0,
                                                   unsigned short* __restrict__ W1T,
                                                   unsigned short* __restrict__ W2T) {
  const int NX = NN * CFEAT;
  const int NO = NCLS * NN;
  const int NW1 = INDIM * HIDD;
  const int NW2 = HIDD * NCLS;
  const int total = NX + NO + NW1 + NW2;
  for (int idx = blockIdx.x * 256 + threadIdx.x; idx < total; idx += gridDim.x * 256) {
    if (idx < NX) {
      int i = idx >> 9, c = idx & 511;
      comb[(size_t)i * INDIM + c] = f2b(X[idx]);
    } else if (idx < NX + NO) {
      int t = idx - NX;
      int c = t >> 13, i = t & 8191;
      curT0[ilv_off(c, i >> 3) + (i & 7)] = f2fp8(onehot[(size_t)i * NCLS + c]);
    } else if (idx < NX + NO + NW1) {
      int t = idx - NX - NO;
      int k = t >> 10, n = t & 1023;
      W1T[(size_t)n * INDIM + k] = f2b(W1[t]);
    } else {
      int t = idx - NX - NO - NW1;
      int k = t / NCLS, c = t - k * NCLS;
      W2T[(size_t)c * HIDD + k] = f2b(W2[t]);
    }
  }
}

// ---------------------------------------------------------------------------
// hop: next = softmax((A8 @ curT^T) * 2^-20) ; fp8 MFMA 16x16x32.
// block = 16 output rows, 8 waves split K (1024 each), LDS reduce + softmax.
// A and B in interleaved layout: every wave-load is a contiguous 512B
// (8 x 64B lines vs 16 x 32B segments before -> half the L1 transactions).
// Epilogue parallelized across waves 0..3 (one accumulator reg r each).
// ---------------------------------------------------------------------------
__global__ __launch_bounds__(512) void hop_kernel(const unsigned char* __restrict__ A8,
                                                  const unsigned char* __restrict__ curT,
                                                  unsigned char* __restrict__ nextT,
                                                  unsigned short* __restrict__ comb,
                                                  int hop) {
  __shared__ float red[8][16][NPAD];
  const int lane = threadIdx.x & 63;
  const int wave = threadIdx.x >> 6;
  const int l15 = lane & 15;
  const int kg = lane >> 4;
  const long* ap  = (const long*)(A8  + (size_t)blockIdx.x * 131072 + (size_t)wave * 16384) + lane;
  const long* bp0 = (const long*)(curT +                              (size_t)wave * 16384) + lane;
  const long* bp1 = (const long*)(curT + 131072                     + (size_t)wave * 16384) + lane;
  const long* bp2 = (const long*)(curT + 262144                     + (size_t)wave * 16384) + lane;
  f32x4 acc0 = {0.f, 0.f, 0.f, 0.f}, acc1 = {0.f, 0.f, 0.f, 0.f}, acc2 = {0.f, 0.f, 0.f, 0.f};
#pragma unroll 4
  for (int t = 0; t < 32; ++t) {
    long a  = ap[t * 64];
    long b0 = bp0[t * 64];
    long b1 = bp1[t * 64];
    long b2 = bp2[t * 64];
    acc0 = __builtin_amdgcn_mfma_f32_16x16x32_fp8_fp8(a, b0, acc0, 0, 0, 0);
    acc1 = __builtin_amdgcn_mfma_f32_16x16x32_fp8_fp8(a, b1, acc1, 0, 0, 0);
    acc2 = __builtin_amdgcn_mfma_f32_16x16x32_fp8_fp8(a, b2, acc2, 0, 0, 0);
  }
#pragma unroll
  for (int r = 0; r < 4; ++r) {
    red[wave][kg * 4 + r][l15] = acc0[r];
    red[wave][kg * 4 + r][16 + l15] = acc1[r];
    red[wave][kg * 4 + r][32 + l15] = acc2[r];
  }
  __syncthreads();
  if (wave < 4) {
    const int rr = kg * 4 + wave;  // wave w handles accumulator register r = w
    float v0 = 0.f, v1 = 0.f, v2 = 0.f;
#pragma unroll
    for (int w = 0; w < 8; ++w) {
      v0 += red[w][rr][l15];
      v1 += red[w][rr][16 + l15];
      v2 += red[w][rr][32 + l15];
    }
    v0 *= A_INV_SCALE; v1 *= A_INV_SCALE; v2 *= A_INV_SCALE;
    const bool ok2 = l15 < 8;  // cols 32..39 valid, 40..47 are padding
    float m = fmaxf(v0, v1);
    if (ok2) m = fmaxf(m, v2);
#pragma unroll
    for (int s = 1; s < 16; s <<= 1) m = fmaxf(m, __shfl_xor(m, s));
    float e0 = __expf(v0 - m);
    float e1 = __expf(v1 - m);
    float e2 = ok2 ? __expf(v2 - m) : 0.f;
    float ssum = e0 + e1 + e2;
#pragma unroll
    for (int s = 1; s < 16; s <<= 1) ssum += __shfl_xor(ssum, s);
    const float inv = 1.f / ssum;
    const size_t i = (size_t)blockIdx.x * 16 + rr;
    const float p0 = e0 * inv;
    const float p1 = e1 * inv;
    // interleaved writes into nextT (row = class c, col = node i)
    const int G = (int)(i >> 3);
    const size_t joff = (size_t)(G >> 7) * 16384 + (size_t)((G >> 2) & 31) * 512 +
                        (size_t)(G & 3) * 128 + (i & 7);
    nextT[joff + (size_t)l15 * 8] = f2fp8(p0);
    nextT[131072 + joff + (size_t)l15 * 8] = f2fp8(p1);
    const size_t cbase = i * INDIM + CFEAT + (size_t)hop * NCLS;
    comb[cbase + l15] = f2b(p0);
    comb[cbase + 16 + l15] = f2b(p1);
    if (ok2) {
      const float p2 = e2 * inv;
      nextT[262144 + joff + (size_t)l15 * 8] = f2fp8(p2);
      comb[cbase + 32 + l15] = f2b(p2);
    }
  }
}

// ---------------------------------------------------------------------------
// GEMM1: h = relu(combined @ W1 + b1), bf16 out. tile 64(M) x 128(N), 4 waves.
// ---------------------------------------------------------------------------
__global__ __launch_bounds__(256) void gemm1_kernel(const unsigned short* __restrict__ comb,
                                                    const unsigned short* __restrict__ W1T,
                                                    const float* __restrict__ bias1,
                                                    unsigned short* __restrict__ h) {
  const int lane = threadIdx.x & 63;
  const int wave = threadIdx.x >> 6;
  const int l15 = lane & 15;
  const int kg = lane >> 4;
  const int bm = blockIdx.x & 127;
  const int bn = blockIdx.x >> 7;
  const size_t arow = (size_t)bm * 64 + wave * 16 + l15;
  const bf16x8* ap = (const bf16x8*)(comb + arow * INDIM + (size_t)kg * 8);
  const bf16x8* bp[8];
#pragma unroll
  for (int tt = 0; tt < 8; ++tt)
    bp[tt] = (const bf16x8*)(W1T + (size_t)(bn * 128 + tt * 16 + l15) * INDIM + (size_t)kg * 8);
  f32x4 acc[8] = {};
#pragma unroll 3
  for (int kk = 0; kk < INDIM; kk += 32) {
    bf16x8 a = *ap; ap += 4;
#pragma unroll
    for (int tt = 0; tt < 8; ++tt) {
      bf16x8 b = *bp[tt]; bp[tt] += 4;
      acc[tt] = __builtin_amdgcn_mfma_f32_16x16x32_bf16(a, b, acc[tt], 0, 0, 0);
    }
  }
#pragma unroll
  for (int tt = 0; tt < 8; ++tt) {
    const int n = bn * 128 + tt * 16 + l15;
    const float bv = bias1[n];
#pragma unroll
    for (int r = 0; r < 4; ++r) {
      const size_t i = (size_t)bm * 64 + wave * 16 + kg * 4 + r;
      float v = acc[tt][r] + bv;
      h[i * HIDD + n] = f2b(v > 0.f ? v : 0.f);
    }
  }
}

// ---------------------------------------------------------------------------
// GEMM2: out = h @ W2 + b2 (fp32 out). bf16 MFMA, 4-wave K-split + LDS reduce.
// ---------------------------------------------------------------------------
__global__ __launch_bounds__(256) void gemm2_kernel(const unsigned short* __restrict__ h,
                                                    const unsigned short* __restrict__ W2T,
                                                    const float* __restrict__ bias2,
                                                    float* __restrict__ out) {
  __shared__ float red[4][16][NPAD];
  const int lane = threadIdx.x & 63;
  const int wave = threadIdx.x >> 6;
  const int l15 = lane & 15;
  const int kg = lane >> 4;
  const size_t arow = (size_t)blockIdx.x * 16 + l15;
  const size_t kbase = (size_t)wave * 256 + (size_t)kg * 8;
  const bf16x8* ap = (const bf16x8*)(h + arow * HIDD + kbase);
  const bf16x8* bp0 = (const bf16x8*)(W2T + (size_t)l15 * HIDD + kbase);
  const bf16x8* bp1 = (const bf16x8*)(W2T + (size_t)(16 + l15) * HIDD + kbase);
  const bf16x8* bp2 = (const bf16x8*)(W2T + (size_t)(32 + l15) * HIDD + kbase);
  f32x4 acc0 = {0.f, 0.f, 0.f, 0.f}, acc1 = {0.f, 0.f, 0.f, 0.f}, acc2 = {0.f, 0.f, 0.f, 0.f};
#pragma unroll
  for (int kk = 0; kk < 256; kk += 32) {
    bf16x8 a = *ap; ap += 4;
    bf16x8 vb0 = *bp0; bp0 += 4;
    bf16x8 vb1 = *bp1; bp1 += 4;
    bf16x8 vb2 = *bp2; bp2 += 4;
    acc0 = __builtin_amdgcn_mfma_f32_16x16x32_bf16(a, vb0, acc0, 0, 0, 0);
    acc1 = __builtin_amdgcn_mfma_f32_16x16x32_bf16(a, vb1, acc1, 0, 0, 0);
    acc2 = __builtin_amdgcn_mfma_f32_16x16x32_bf16(a, vb2, acc2, 0, 0, 0);
  }
#pragma unroll
  for (int r = 0; r < 4; ++r) {
    red[wave][kg * 4 + r][l15] = acc0[r];
    red[wave][kg * 4 + r][16 + l15] = acc1[r];
    red[wave][kg * 4 + r][32 + l15] = acc2[r];
  }
  __syncthreads();
  if (wave == 0) {
#pragma unroll
    for (int r = 0; r < 4; ++r) {
      const int rr = kg * 4 + r;
      float v0 = red[0][rr][l15] + red[1][rr][l15] + red[2][rr][l15] + red[3][rr][l15];
      float v1 = red[0][rr][16 + l15] + red[1][rr][16 + l15] + red[2][rr][16 + l15] + red[3][rr][16 + l15];
      float v2 = red[0][rr][32 + l15] + red[1][rr][32 + l15] + red[2][rr][32 + l15] + red[3][rr][32 + l15];
      const size_t i = (size_t)blockIdx.x * 16 + rr;
      out[i * NCLS + l15] = v0 + bias2[l15];
      out[i * NCLS + 16 + l15] = v1 + bias2[16 + l15];
      if (l15 < 8) out[i * NCLS + 32 + l15] = v2 + bias2[32 + l15];
    }
  }
}

extern "C" void kernel_launch(void* const* d_in, const int* in_sizes, int n_in,
                              void* d_out, int out_size, void* d_ws, size_t ws_size,
                              hipStream_t stream) {
  const float* X = (const float*)d_in[0];
  const float* onehot = (const float*)d_in[1];
  const float* adj = (const float*)d_in[2];
  const float* W1 = (const float*)d_in[3];
  const float* b1 = (const float*)d_in[4];
  const float* W2 = (const float*)d_in[5];
  const float* b2 = (const float*)d_in[6];
  float* out = (float*)d_out;
  char* ws = (char*)d_ws;

  // workspace layout (bytes)
  unsigned char*  A8   = (unsigned char*)(ws);                 // 8192*8192*1   = 67108864
  unsigned char*  cur0 = (unsigned char*)(ws + 67108864ull);   // 48*8192*1     = 393216
  unsigned char*  cur1 = (unsigned char*)(ws + 67502080ull);   // 48*8192*1     = 393216
  unsigned short* comb = (unsigned short*)(ws + 67895296ull);  // 8192*672*2    = 11010048
  unsigned short* W1T  = (unsigned short*)(ws + 78905344ull);  // 1024*672*2    = 1376256
  unsigned short* W2T  = (unsigned short*)(ws + 80281600ull);  // 48*1024*2     = 98304
  unsigned short* hbuf = (unsigned short*)(ws + 80379904ull);  // 8192*1024*2   = 16777216
  // total = 97157120 bytes

  normalize_kernel<<<NN, 256, 0, stream>>>(adj, A8);
  prep_kernel<<<2048, 256, 0, stream>>>(X, onehot, W1, W2, comb, cur0, W1T, W2T);
  hop_kernel<<<NN / 16, 512, 0, stream>>>(A8, cur0, cur1, comb, 0);
  hop_kernel<<<NN / 16, 512, 0, stream>>>(A8, cur1, cur0, comb, 1);
  hop_kernel<<<NN / 16, 512, 0, stream>>>(A8, cur0, cur1, comb, 2);
  hop_kernel<<<NN / 16, 512, 0, stream>>>(A8, cur1, cur0, comb, 3);
  gemm1_kernel<<<1024, 256, 0, stream>>>(comb, W1T, b1, hbuf);
  gemm2_kernel<<<NN / 16, 256, 0, stream>>>(hbuf, W2T, b2, out);
}

// Round 3
// 557.375 us; speedup vs baseline: 1.2574x; 1.0808x over previous
//
#include <hip/hip_runtime.h>
#include <hip/hip_bf16.h>

#define NN 8192
#define CFEAT 512
#define NCLS 40
#define NPAD 48
#define INDIM 672
#define HIDD 1024

typedef __attribute__((ext_vector_type(8))) short bf16x8;
typedef __attribute__((ext_vector_type(4))) float f32x4;
typedef __attribute__((ext_vector_type(2))) long l64x2;

#define A_SCALE 1048576.0f        // 2^20
#define A_INV_SCALE 9.5367431640625e-07f  // 2^-20

__device__ inline unsigned short f2b(float f) {
  union { __hip_bfloat16 b; unsigned short u; } cv;
  cv.b = __float2bfloat16(f);
  return cv.u;
}

__device__ inline unsigned char f2fp8(float f) {
  int pk = __builtin_amdgcn_cvt_pk_fp8_f32(f, 0.f, 0, false);
  return (unsigned char)(pk & 0xff);
}

// Interleaved fp8 matrix layout so hop_kernel wave-loads are CONTIGUOUS 512B:
// byte of (row r, col k), G=k>>3:
//   (r>>4)*131072 + (G>>7)*16384 + ((G>>2)&31)*512 + (G&3)*128 + (r&15)*8 + (k&7)
__device__ inline size_t ilv_off(int r, int G) {
  return (size_t)(r >> 4) * 131072 + (size_t)(G >> 7) * 16384 +
         (size_t)((G >> 2) & 31) * 512 + (size_t)(G & 3) * 128 + (size_t)(r & 15) * 8;
}

// ---------------------------------------------------------------------------
// K1: A8row[i][k] = fp8_e4m3( 2^20 * sigmoid(adj[i][k]) / (rowsum + 1e-8) )
// one block per row; contiguous row-major writes (full 64B lines -> clean HBM
// write traffic; the interleave is produced by relayout_kernel below).
// ---------------------------------------------------------------------------
__global__ __launch_bounds__(256) void normalize_kernel(const float* __restrict__ adj,
                                                        unsigned char* __restrict__ A8row) {
  __shared__ float wsum[4];
  const int t = threadIdx.x;
  const size_t i = blockIdx.x;
  const float4* src = (const float4*)(adj + i * NN);
  float4 v[8];
  float sum = 0.f;
#pragma unroll
  for (int it = 0; it < 8; ++it) {
    float4 x = src[it * 256 + t];
    float s0 = __builtin_amdgcn_rcpf(1.f + __expf(-x.x));
    float s1 = __builtin_amdgcn_rcpf(1.f + __expf(-x.y));
    float s2 = __builtin_amdgcn_rcpf(1.f + __expf(-x.z));
    float s3 = __builtin_amdgcn_rcpf(1.f + __expf(-x.w));
    v[it] = make_float4(s0, s1, s2, s3);
    sum += (s0 + s1) + (s2 + s3);
  }
#pragma unroll
  for (int m = 1; m < 64; m <<= 1) sum += __shfl_xor(sum, m);
  if ((t & 63) == 0) wsum[t >> 6] = sum;
  __syncthreads();
  const float dinv = A_SCALE / (wsum[0] + wsum[1] + wsum[2] + wsum[3] + 1e-8f);
  unsigned int* dst = (unsigned int*)(A8row + i * NN);
#pragma unroll
  for (int it = 0; it < 8; ++it) {
    int lo = __builtin_amdgcn_cvt_pk_fp8_f32(v[it].x * dinv, v[it].y * dinv, 0, false);
    int pk = __builtin_amdgcn_cvt_pk_fp8_f32(v[it].z * dinv, v[it].w * dinv, lo, true);
    dst[it * 256 + t] = (unsigned int)pk;
  }
}

// ---------------------------------------------------------------------------
// relayout: A8row (row-major) -> A8i (interleaved). One block per 16-row
// group; 4 chunks of 16 rows x 2048 cols staged in LDS. Key property: for a
// chunk m, the interleaved output is EXACTLY linear: out byte = m*32768 + v*16
// where v = g*8 + q encodes (granule g, row-pair q). Both global sides are
// perfectly coalesced; LDS pays a modest (~4-way) b64 read conflict.
// ---------------------------------------------------------------------------
__global__ __launch_bounds__(256) void relayout_kernel(const unsigned char* __restrict__ A8row,
                                                       unsigned char* __restrict__ A8i) {
  __shared__ unsigned char tile[16][2064];  // 2048 + 16B pad to spread banks
  const int t = threadIdx.x;
  const size_t grp = blockIdx.x;  // 0..511
  const unsigned char* src = A8row + grp * 16 * NN;
  unsigned char* dst = A8i + grp * 131072;
  for (int m = 0; m < 4; ++m) {
    if (m) __syncthreads();
#pragma unroll
    for (int s = 0; s < 8; ++s) {
      const int u = t + 256 * s;
      const int row = u >> 7, col16 = u & 127;
      *(uint4*)&tile[row][col16 * 16] =
          *(const uint4*)(src + (size_t)row * NN + (size_t)m * 2048 + (size_t)col16 * 16);
    }
    __syncthreads();
#pragma unroll
    for (int s = 0; s < 8; ++s) {
      const int v = t + 256 * s;
      const int g = v >> 3, q = v & 7;
      l64x2 val;
      val[0] = *(const long*)&tile[2 * q][g * 8];
      val[1] = *(const long*)&tile[2 * q + 1][g * 8];
      *(l64x2*)(dst + (size_t)m * 32768 + (size_t)v * 16) = val;
    }
  }
}

// ---------------------------------------------------------------------------
// prep: X -> combined[:, :512] bf16 ; onehot -> curT0 [48 x 8192] fp8
// (interleaved layout); W1 -> W1T bf16 ; W2 -> W2T bf16. pad rows of curT/W2T
// stay poisoned (finite or NaN is fine: per-lane isolated + masked downstream).
// ---------------------------------------------------------------------------
__global__ __launch_bounds__(256) void prep_kernel(const float* __restrict__ X,
                                                   const float* __restrict__ onehot,
                                                   const float* __restrict__ W1,
                                                   const float* __restrict__ W2,
                                                   unsigned short* __restrict__ comb,
                                                   unsigned char* __restrict__ curT0,
                                                   unsigned short* __restrict__ W1T,
                                                   unsigned short* __restrict__ W2T) {
  const int NX = NN * CFEAT;
  const int NO = NCLS * NN;
  const int NW1 = INDIM * HIDD;
  const int NW2 = HIDD * NCLS;
  const int total = NX + NO + NW1 + NW2;
  for (int idx = blockIdx.x * 256 + threadIdx.x; idx < total; idx += gridDim.x * 256) {
    if (idx < NX) {
      int i = idx >> 9, c = idx & 511;
      comb[(size_t)i * INDIM + c] = f2b(X[idx]);
    } else if (idx < NX + NO) {
      int t = idx - NX;
      int c = t >> 13, i = t & 8191;
      curT0[ilv_off(c, i >> 3) + (i & 7)] = f2fp8(onehot[(size_t)i * NCLS + c]);
    } else if (idx < NX + NO + NW1) {
      int t = idx - NX - NO;
      int k = t >> 10, n = t & 1023;
      W1T[(size_t)n * INDIM + k] = f2b(W1[t]);
    } else {
      int t = idx - NX - NO - NW1;
      int k = t / NCLS, c = t - k * NCLS;
      W2T[(size_t)c * HIDD + k] = f2b(W2[t]);
    }
  }
}

// ---------------------------------------------------------------------------
// hop: next = softmax((A8 @ curT^T) * 2^-20) ; fp8 MFMA 16x16x32.
// block = 16 output rows, 8 waves split K (1024 each), LDS reduce + softmax.
// A and B in interleaved layout: every wave-load is a contiguous 512B.
// Epilogue parallelized across waves 0..3 (one accumulator reg r each).
// ---------------------------------------------------------------------------
__global__ __launch_bounds__(512) void hop_kernel(const unsigned char* __restrict__ A8,
                                                  const unsigned char* __restrict__ curT,
                                                  unsigned char* __restrict__ nextT,
                                                  unsigned short* __restrict__ comb,
                                                  int hop) {
  __shared__ float red[8][16][NPAD];
  const int lane = threadIdx.x & 63;
  const int wave = threadIdx.x >> 6;
  const int l15 = lane & 15;
  const int kg = lane >> 4;
  const long* ap  = (const long*)(A8  + (size_t)blockIdx.x * 131072 + (size_t)wave * 16384) + lane;
  const long* bp0 = (const long*)(curT +                              (size_t)wave * 16384) + lane;
  const long* bp1 = (const long*)(curT + 131072                     + (size_t)wave * 16384) + lane;
  const long* bp2 = (const long*)(curT + 262144                     + (size_t)wave * 16384) + lane;
  f32x4 acc0 = {0.f, 0.f, 0.f, 0.f}, acc1 = {0.f, 0.f, 0.f, 0.f}, acc2 = {0.f, 0.f, 0.f, 0.f};
#pragma unroll 4
  for (int t = 0; t < 32; ++t) {
    long a  = ap[t * 64];
    long b0 = bp0[t * 64];
    long b1 = bp1[t * 64];
    long b2 = bp2[t * 64];
    acc0 = __builtin_amdgcn_mfma_f32_16x16x32_fp8_fp8(a, b0, acc0, 0, 0, 0);
    acc1 = __builtin_amdgcn_mfma_f32_16x16x32_fp8_fp8(a, b1, acc1, 0, 0, 0);
    acc2 = __builtin_amdgcn_mfma_f32_16x16x32_fp8_fp8(a, b2, acc2, 0, 0, 0);
  }
#pragma unroll
  for (int r = 0; r < 4; ++r) {
    red[wave][kg * 4 + r][l15] = acc0[r];
    red[wave][kg * 4 + r][16 + l15] = acc1[r];
    red[wave][kg * 4 + r][32 + l15] = acc2[r];
  }
  __syncthreads();
  if (wave < 4) {
    const int rr = kg * 4 + wave;  // wave w handles accumulator register r = w
    float v0 = 0.f, v1 = 0.f, v2 = 0.f;
#pragma unroll
    for (int w = 0; w < 8; ++w) {
      v0 += red[w][rr][l15];
      v1 += red[w][rr][16 + l15];
      v2 += red[w][rr][32 + l15];
    }
    v0 *= A_INV_SCALE; v1 *= A_INV_SCALE; v2 *= A_INV_SCALE;
    const bool ok2 = l15 < 8;  // cols 32..39 valid, 40..47 are padding
    float m = fmaxf(v0, v1);
    if (ok2) m = fmaxf(m, v2);
#pragma unroll
    for (int s = 1; s < 16; s <<= 1) m = fmaxf(m, __shfl_xor(m, s));
    float e0 = __expf(v0 - m);
    float e1 = __expf(v1 - m);
    float e2 = ok2 ? __expf(v2 - m) : 0.f;
    float ssum = e0 + e1 + e2;
#pragma unroll
    for (int s = 1; s < 16; s <<= 1) ssum += __shfl_xor(ssum, s);
    const float inv = 1.f / ssum;
    const size_t i = (size_t)blockIdx.x * 16 + rr;
    const float p0 = e0 * inv;
    const float p1 = e1 * inv;
    // interleaved writes into nextT (row = class c, col = node i)
    const int G = (int)(i >> 3);
    const size_t joff = (size_t)(G >> 7) * 16384 + (size_t)((G >> 2) & 31) * 512 +
                        (size_t)(G & 3) * 128 + (i & 7);
    nextT[joff + (size_t)l15 * 8] = f2fp8(p0);
    nextT[131072 + joff + (size_t)l15 * 8] = f2fp8(p1);
    const size_t cbase = i * INDIM + CFEAT + (size_t)hop * NCLS;
    comb[cbase + l15] = f2b(p0);
    comb[cbase + 16 + l15] = f2b(p1);
    if (ok2) {
      const float p2 = e2 * inv;
      nextT[262144 + joff + (size_t)l15 * 8] = f2fp8(p2);
      comb[cbase + 32 + l15] = f2b(p2);
    }
  }
}

// ---------------------------------------------------------------------------
// GEMM1: h = relu(combined @ W1 + b1), bf16 out. tile 64(M) x 128(N), 4 waves.
// ---------------------------------------------------------------------------
__global__ __launch_bounds__(256) void gemm1_kernel(const unsigned short* __restrict__ comb,
                                                    const unsigned short* __restrict__ W1T,
                                                    const float* __restrict__ bias1,
                                                    unsigned short* __restrict__ h) {
  const int lane = threadIdx.x & 63;
  const int wave = threadIdx.x >> 6;
  const int l15 = lane & 15;
  const int kg = lane >> 4;
  const int bm = blockIdx.x & 127;
  const int bn = blockIdx.x >> 7;
  const size_t arow = (size_t)bm * 64 + wave * 16 + l15;
  const bf16x8* ap = (const bf16x8*)(comb + arow * INDIM + (size_t)kg * 8);
  const bf16x8* bp[8];
#pragma unroll
  for (int tt = 0; tt < 8; ++tt)
    bp[tt] = (const bf16x8*)(W1T + (size_t)(bn * 128 + tt * 16 + l15) * INDIM + (size_t)kg * 8);
  f32x4 acc[8] = {};
#pragma unroll 3
  for (int kk = 0; kk < INDIM; kk += 32) {
    bf16x8 a = *ap; ap += 4;
#pragma unroll
    for (int tt = 0; tt < 8; ++tt) {
      bf16x8 b = *bp[tt]; bp[tt] += 4;
      acc[tt] = __builtin_amdgcn_mfma_f32_16x16x32_bf16(a, b, acc[tt], 0, 0, 0);
    }
  }
#pragma unroll
  for (int tt = 0; tt < 8; ++tt) {
    const int n = bn * 128 + tt * 16 + l15;
    const float bv = bias1[n];
#pragma unroll
    for (int r = 0; r < 4; ++r) {
      const size_t i = (size_t)bm * 64 + wave * 16 + kg * 4 + r;
      float v = acc[tt][r] + bv;
      h[i * HIDD + n] = f2b(v > 0.f ? v : 0.f);
    }
  }
}

// ---------------------------------------------------------------------------
// GEMM2: out = h @ W2 + b2 (fp32 out). bf16 MFMA, 4-wave K-split + LDS reduce.
// ---------------------------------------------------------------------------
__global__ __launch_bounds__(256) void gemm2_kernel(const unsigned short* __restrict__ h,
                                                    const unsigned short* __restrict__ W2T,
                                                    const float* __restrict__ bias2,
                                                    float* __restrict__ out) {
  __shared__ float red[4][16][NPAD];
  const int lane = threadIdx.x & 63;
  const int wave = threadIdx.x >> 6;
  const int l15 = lane & 15;
  const int kg = lane >> 4;
  const size_t arow = (size_t)blockIdx.x * 16 + l15;
  const size_t kbase = (size_t)wave * 256 + (size_t)kg * 8;
  const bf16x8* ap = (const bf16x8*)(h + arow * HIDD + kbase);
  const bf16x8* bp0 = (const bf16x8*)(W2T + (size_t)l15 * HIDD + kbase);
  const bf16x8* bp1 = (const bf16x8*)(W2T + (size_t)(16 + l15) * HIDD + kbase);
  const bf16x8* bp2 = (const bf16x8*)(W2T + (size_t)(32 + l15) * HIDD + kbase);
  f32x4 acc0 = {0.f, 0.f, 0.f, 0.f}, acc1 = {0.f, 0.f, 0.f, 0.f}, acc2 = {0.f, 0.f, 0.f, 0.f};
#pragma unroll
  for (int kk = 0; kk < 256; kk += 32) {
    bf16x8 a = *ap; ap += 4;
    bf16x8 vb0 = *bp0; bp0 += 4;
    bf16x8 vb1 = *bp1; bp1 += 4;
    bf16x8 vb2 = *bp2; bp2 += 4;
    acc0 = __builtin_amdgcn_mfma_f32_16x16x32_bf16(a, vb0, acc0, 0, 0, 0);
    acc1 = __builtin_amdgcn_mfma_f32_16x16x32_bf16(a, vb1, acc1, 0, 0, 0);
    acc2 = __builtin_amdgcn_mfma_f32_16x16x32_bf16(a, vb2, acc2, 0, 0, 0);
  }
#pragma unroll
  for (int r = 0; r < 4; ++r) {
    red[wave][kg * 4 + r][l15] = acc0[r];
    red[wave][kg * 4 + r][16 + l15] = acc1[r];
    red[wave][kg * 4 + r][32 + l15] = acc2[r];
  }
  __syncthreads();
  if (wave == 0) {
#pragma unroll
    for (int r = 0; r < 4; ++r) {
      const int rr = kg * 4 + r;
      float v0 = red[0][rr][l15] + red[1][rr][l15] + red[2][rr][l15] + red[3][rr][l15];
      float v1 = red[0][rr][16 + l15] + red[1][rr][16 + l15] + red[2][rr][16 + l15] + red[3][rr][16 + l15];
      float v2 = red[0][rr][32 + l15] + red[1][rr][32 + l15] + red[2][rr][32 + l15] + red[3][rr][32 + l15];
      const size_t i = (size_t)blockIdx.x * 16 + rr;
      out[i * NCLS + l15] = v0 + bias2[l15];
      out[i * NCLS + 16 + l15] = v1 + bias2[16 + l15];
      if (l15 < 8) out[i * NCLS + 32 + l15] = v2 + bias2[32 + l15];
    }
  }
}

extern "C" void kernel_launch(void* const* d_in, const int* in_sizes, int n_in,
                              void* d_out, int out_size, void* d_ws, size_t ws_size,
                              hipStream_t stream) {
  const float* X = (const float*)d_in[0];
  const float* onehot = (const float*)d_in[1];
  const float* adj = (const float*)d_in[2];
  const float* W1 = (const float*)d_in[3];
  const float* b1 = (const float*)d_in[4];
  const float* W2 = (const float*)d_in[5];
  const float* b2 = (const float*)d_in[6];
  float* out = (float*)d_out;
  char* ws = (char*)d_ws;

  // workspace layout (bytes)
  unsigned char*  A8i  = (unsigned char*)(ws);                  // 67108864 (interleaved)
  unsigned char*  A8r  = (unsigned char*)(ws + 67108864ull);    // 67108864 (row-major)
  unsigned char*  cur0 = (unsigned char*)(ws + 134217728ull);   // 393216
  unsigned char*  cur1 = (unsigned char*)(ws + 134610944ull);   // 393216
  unsigned short* comb = (unsigned short*)(ws + 135004160ull);  // 11010048
  unsigned short* W1T  = (unsigned short*)(ws + 146014208ull);  // 1376256
  unsigned short* W2T  = (unsigned short*)(ws + 147390464ull);  // 98304
  unsigned short* hbuf = (unsigned short*)(ws + 147488768ull);  // 16777216
  // total = 164265984 bytes

  normalize_kernel<<<NN, 256, 0, stream>>>(adj, A8r);
  relayout_kernel<<<NN / 16, 256, 0, stream>>>(A8r, A8i);
  prep_kernel<<<2048, 256, 0, stream>>>(X, onehot, W1, W2, comb, cur0, W1T, W2T);
  hop_kernel<<<NN / 16, 512, 0, stream>>>(A8i, cur0, cur1, comb, 0);
  hop_kernel<<<NN / 16, 512, 0, stream>>>(A8i, cur1, cur0, comb, 1);
  hop_kernel<<<NN / 16, 512, 0, stream>>>(A8i, cur0, cur1, comb, 2);
  hop_kernel<<<NN / 16, 512, 0, stream>>>(A8i, cur1, cur0, comb, 3);
  gemm1_kernel<<<1024, 256, 0, stream>>>(comb, W1T, b1, hbuf);
  gemm2_kernel<<<NN / 16, 256, 0, stream>>>(hbuf, W2T, b2, out);
}

// Round 4
// 539.563 us; speedup vs baseline: 1.2989x; 1.0330x over previous
//
#include <hip/hip_runtime.h>
#include <hip/hip_bf16.h>

#define NN 8192
#define CFEAT 512
#define NCLS 40
#define NPAD 48
#define INDIM 672
#define HIDD 1024

typedef __attribute__((ext_vector_type(8))) short bf16x8;
typedef __attribute__((ext_vector_type(4))) float f32x4;
typedef __attribute__((ext_vector_type(2))) long l64x2;

// A8i holds e4m3(32 * sigmoid(adj)); d_inv applied in hop epilogue (row scaling
// commutes with the matmul). dinv[] stores 1/(32*(rowsum+1e-8)).
#define SIG_SCALE 32.0f

__device__ inline unsigned short f2b(float f) {
  union { __hip_bfloat16 b; unsigned short u; } cv;
  cv.b = __float2bfloat16(f);
  return cv.u;
}

__device__ inline unsigned char f2fp8(float f) {
  int pk = __builtin_amdgcn_cvt_pk_fp8_f32(f, 0.f, 0, false);
  return (unsigned char)(pk & 0xff);
}

// Interleaved fp8 matrix layout so hop_kernel wave-loads are CONTIGUOUS 512B:
// byte of (row r, col k), G=k>>3:
//   (r>>4)*131072 + (G>>7)*16384 + ((G>>2)&31)*512 + (G&3)*128 + (r&15)*8 + (k&7)
// Within a 16-row group this is LINEAR in G: byte = G*128 + (r&15)*8 + (k&7).
__device__ inline size_t ilv_off(int r, int G) {
  return (size_t)(r >> 4) * 131072 + (size_t)(G >> 7) * 16384 +
         (size_t)((G >> 2) & 31) * 512 + (size_t)(G & 3) * 128 + (size_t)(r & 15) * 8;
}

// ---------------------------------------------------------------------------
// sig: A8i[grp] = interleaved e4m3(32*sigmoid(adj rows 16grp..16grp+15));
//      dinv[i] = 1/(32*(rowsum_i + 1e-8)).
// One block per 16-row group, 16 waves (one row each). Per 2048-col chunk:
// compute sigmoid -> fp8 into LDS (conflict-free), then write the chunk's
// 32768B interleaved block as fully contiguous stores (out byte = v*16,
// v = g_local*8 + q, rows 2q/2q+1 at +-8). No relayout pass, no cross-wave
// dependency (fixed quantization scale; d_inv deferred to hop epilogue).
// ---------------------------------------------------------------------------
__global__ __launch_bounds__(1024) void sig_kernel(const float* __restrict__ adj,
                                                   unsigned char* __restrict__ A8i,
                                                   float* __restrict__ dinv) {
  __shared__ unsigned char lds[16][2056];  // 2048 + 8B pad (breaks 8-way banks)
  const int t = threadIdx.x;
  const int wave = t >> 6;   // row within group
  const int lane = t & 63;
  const size_t grp = blockIdx.x;  // 0..511
  const size_t row = grp * 16 + wave;
  const float4* src = (const float4*)(adj + row * NN);
  unsigned char* dst = A8i + grp * 131072;
  float sum = 0.f;
  for (int m = 0; m < 4; ++m) {
    // compute phase: wave covers cols [m*2048, m*2048+2048) of its row
#pragma unroll
    for (int it = 0; it < 8; ++it) {
      const int idx = it * 64 + lane;  // float4 index within chunk: 0..511
      float4 x = src[m * 512 + idx];
      float s0 = __builtin_amdgcn_rcpf(1.f + __expf(-x.x));
      float s1 = __builtin_amdgcn_rcpf(1.f + __expf(-x.y));
      float s2 = __builtin_amdgcn_rcpf(1.f + __expf(-x.z));
      float s3 = __builtin_amdgcn_rcpf(1.f + __expf(-x.w));
      sum += (s0 + s1) + (s2 + s3);
      int lo = __builtin_amdgcn_cvt_pk_fp8_f32(s0 * SIG_SCALE, s1 * SIG_SCALE, 0, false);
      int pk = __builtin_amdgcn_cvt_pk_fp8_f32(s2 * SIG_SCALE, s3 * SIG_SCALE, lo, true);
      *(unsigned int*)&lds[wave][idx * 4] = (unsigned int)pk;
    }
    __syncthreads();
    // output phase: 32768B contiguous (2 passes x 1024 threads x 16B)
#pragma unroll
    for (int pass = 0; pass < 2; ++pass) {
      const int v = pass * 1024 + t;  // 0..2047
      const int g = v >> 3, q = v & 7;
      l64x2 val;
      val[0] = *(const long*)&lds[2 * q][g * 8];
      val[1] = *(const long*)&lds[2 * q + 1][g * 8];
      *(l64x2*)(dst + (size_t)m * 32768 + (size_t)v * 16) = val;
    }
    __syncthreads();
  }
#pragma unroll
  for (int s = 1; s < 64; s <<= 1) sum += __shfl_xor(sum, s);
  if (lane == 0) dinv[row] = 1.f / (SIG_SCALE * (sum + 1e-8f));
}

// ---------------------------------------------------------------------------
// prep: X -> combined[:, :512] bf16 ; onehot -> curT0 [48 x 8192] fp8
// (interleaved layout); W1 -> W1T bf16 ; W2 -> W2T bf16. pad rows of curT/W2T
// stay poisoned (finite or NaN is fine: per-lane isolated + masked downstream).
// ---------------------------------------------------------------------------
__global__ __launch_bounds__(256) void prep_kernel(const float* __restrict__ X,
                                                   const float* __restrict__ onehot,
                                                   const float* __restrict__ W1,
                                                   const float* __restrict__ W2,
                                                   unsigned short* __restrict__ comb,
                                                   unsigned char* __restrict__ curT0,
                                                   unsigned short* __restrict__ W1T,
                                                   unsigned short* __restrict__ W2T) {
  const int NX = NN * CFEAT;
  const int NO = NCLS * NN;
  const int NW1 = INDIM * HIDD;
  const int NW2 = HIDD * NCLS;
  const int total = NX + NO + NW1 + NW2;
  for (int idx = blockIdx.x * 256 + threadIdx.x; idx < total; idx += gridDim.x * 256) {
    if (idx < NX) {
      int i = idx >> 9, c = idx & 511;
      comb[(size_t)i * INDIM + c] = f2b(X[idx]);
    } else if (idx < NX + NO) {
      int t = idx - NX;
      int c = t >> 13, i = t & 8191;
      curT0[ilv_off(c, i >> 3) + (i & 7)] = f2fp8(onehot[(size_t)i * NCLS + c]);
    } else if (idx < NX + NO + NW1) {
      int t = idx - NX - NO;
      int k = t >> 10, n = t & 1023;
      W1T[(size_t)n * INDIM + k] = f2b(W1[t]);
    } else {
      int t = idx - NX - NO - NW1;
      int k = t / NCLS, c = t - k * NCLS;
      W2T[(size_t)c * HIDD + k] = f2b(W2[t]);
    }
  }
}

// ---------------------------------------------------------------------------
// hop: next = softmax(dinv[i] * (A8 @ curT^T)) ; fp8 MFMA 16x16x32.
// block = 16 output rows, 8 waves split K (1024 each), LDS reduce + softmax.
// A and B in interleaved layout: every wave-load is a contiguous 512B.
// Epilogue parallelized across waves 0..3 (one accumulator reg r each);
// per-row d_inv applied here (commutes with the matmul).
// ---------------------------------------------------------------------------
__global__ __launch_bounds__(512) void hop_kernel(const unsigned char* __restrict__ A8,
                                                  const unsigned char* __restrict__ curT,
                                                  const float* __restrict__ dinv,
                                                  unsigned char* __restrict__ nextT,
                                                  unsigned short* __restrict__ comb,
                                                  int hop) {
  __shared__ float red[8][16][NPAD];
  const int lane = threadIdx.x & 63;
  const int wave = threadIdx.x >> 6;
  const int l15 = lane & 15;
  const int kg = lane >> 4;
  const long* ap  = (const long*)(A8  + (size_t)blockIdx.x * 131072 + (size_t)wave * 16384) + lane;
  const long* bp0 = (const long*)(curT +                              (size_t)wave * 16384) + lane;
  const long* bp1 = (const long*)(curT + 131072                     + (size_t)wave * 16384) + lane;
  const long* bp2 = (const long*)(curT + 262144                     + (size_t)wave * 16384) + lane;
  f32x4 acc0 = {0.f, 0.f, 0.f, 0.f}, acc1 = {0.f, 0.f, 0.f, 0.f}, acc2 = {0.f, 0.f, 0.f, 0.f};
#pragma unroll 4
  for (int t = 0; t < 32; ++t) {
    long a  = ap[t * 64];
    long b0 = bp0[t * 64];
    long b1 = bp1[t * 64];
    long b2 = bp2[t * 64];
    acc0 = __builtin_amdgcn_mfma_f32_16x16x32_fp8_fp8(a, b0, acc0, 0, 0, 0);
    acc1 = __builtin_amdgcn_mfma_f32_16x16x32_fp8_fp8(a, b1, acc1, 0, 0, 0);
    acc2 = __builtin_amdgcn_mfma_f32_16x16x32_fp8_fp8(a, b2, acc2, 0, 0, 0);
  }
#pragma unroll
  for (int r = 0; r < 4; ++r) {
    red[wave][kg * 4 + r][l15] = acc0[r];
    red[wave][kg * 4 + r][16 + l15] = acc1[r];
    red[wave][kg * 4 + r][32 + l15] = acc2[r];
  }
  __syncthreads();
  if (wave < 4) {
    const int rr = kg * 4 + wave;  // wave w handles accumulator register r = w
    const size_t i = (size_t)blockIdx.x * 16 + rr;
    const float dv = dinv[i];      // broadcast (same for all l15 lanes)
    float v0 = 0.f, v1 = 0.f, v2 = 0.f;
#pragma unroll
    for (int w = 0; w < 8; ++w) {
      v0 += red[w][rr][l15];
      v1 += red[w][rr][16 + l15];
      v2 += red[w][rr][32 + l15];
    }
    v0 *= dv; v1 *= dv; v2 *= dv;
    const bool ok2 = l15 < 8;  // cols 32..39 valid, 40..47 are padding
    float m = fmaxf(v0, v1);
    if (ok2) m = fmaxf(m, v2);
#pragma unroll
    for (int s = 1; s < 16; s <<= 1) m = fmaxf(m, __shfl_xor(m, s));
    float e0 = __expf(v0 - m);
    float e1 = __expf(v1 - m);
    float e2 = ok2 ? __expf(v2 - m) : 0.f;
    float ssum = e0 + e1 + e2;
#pragma unroll
    for (int s = 1; s < 16; s <<= 1) ssum += __shfl_xor(ssum, s);
    const float inv = 1.f / ssum;
    const float p0 = e0 * inv;
    const float p1 = e1 * inv;
    // interleaved writes into nextT (row = class c, col = node i)
    const int G = (int)(i >> 3);
    const size_t joff = (size_t)(G >> 7) * 16384 + (size_t)((G >> 2) & 31) * 512 +
                        (size_t)(G & 3) * 128 + (i & 7);
    nextT[joff + (size_t)l15 * 8] = f2fp8(p0);
    nextT[131072 + joff + (size_t)l15 * 8] = f2fp8(p1);
    const size_t cbase = i * INDIM + CFEAT + (size_t)hop * NCLS;
    comb[cbase + l15] = f2b(p0);
    comb[cbase + 16 + l15] = f2b(p1);
    if (ok2) {
      const float p2 = e2 * inv;
      nextT[262144 + joff + (size_t)l15 * 8] = f2fp8(p2);
      comb[cbase + 32 + l15] = f2b(p2);
    }
  }
}

// ---------------------------------------------------------------------------
// GEMM1: h = relu(combined @ W1 + b1), bf16 out. tile 64(M) x 128(N), 4 waves.
// ---------------------------------------------------------------------------
__global__ __launch_bounds__(256) void gemm1_kernel(const unsigned short* __restrict__ comb,
                                                    const unsigned short* __restrict__ W1T,
                                                    const float* __restrict__ bias1,
                                                    unsigned short* __restrict__ h) {
  const int lane = threadIdx.x & 63;
  const int wave = threadIdx.x >> 6;
  const int l15 = lane & 15;
  const int kg = lane >> 4;
  const int bm = blockIdx.x & 127;
  const int bn = blockIdx.x >> 7;
  const size_t arow = (size_t)bm * 64 + wave * 16 + l15;
  const bf16x8* ap = (const bf16x8*)(comb + arow * INDIM + (size_t)kg * 8);
  const bf16x8* bp[8];
#pragma unroll
  for (int tt = 0; tt < 8; ++tt)
    bp[tt] = (const bf16x8*)(W1T + (size_t)(bn * 128 + tt * 16 + l15) * INDIM + (size_t)kg * 8);
  f32x4 acc[8] = {};
#pragma unroll 3
  for (int kk = 0; kk < INDIM; kk += 32) {
    bf16x8 a = *ap; ap += 4;
#pragma unroll
    for (int tt = 0; tt < 8; ++tt) {
      bf16x8 b = *bp[tt]; bp[tt] += 4;
      acc[tt] = __builtin_amdgcn_mfma_f32_16x16x32_bf16(a, b, acc[tt], 0, 0, 0);
    }
  }
#pragma unroll
  for (int tt = 0; tt < 8; ++tt) {
    const int n = bn * 128 + tt * 16 + l15;
    const float bv = bias1[n];
#pragma unroll
    for (int r = 0; r < 4; ++r) {
      const size_t i = (size_t)bm * 64 + wave * 16 + kg * 4 + r;
      float v = acc[tt][r] + bv;
      h[i * HIDD + n] = f2b(v > 0.f ? v : 0.f);
    }
  }
}

// ---------------------------------------------------------------------------
// GEMM2: out = h @ W2 + b2 (fp32 out). bf16 MFMA, 4-wave K-split + LDS reduce.
// ---------------------------------------------------------------------------
__global__ __launch_bounds__(256) void gemm2_kernel(const unsigned short* __restrict__ h,
                                                    const unsigned short* __restrict__ W2T,
                                                    const float* __restrict__ bias2,
                                                    float* __restrict__ out) {
  __shared__ float red[4][16][NPAD];
  const int lane = threadIdx.x & 63;
  const int wave = threadIdx.x >> 6;
  const int l15 = lane & 15;
  const int kg = lane >> 4;
  const size_t arow = (size_t)blockIdx.x * 16 + l15;
  const size_t kbase = (size_t)wave * 256 + (size_t)kg * 8;
  const bf16x8* ap = (const bf16x8*)(h + arow * HIDD + kbase);
  const bf16x8* bp0 = (const bf16x8*)(W2T + (size_t)l15 * HIDD + kbase);
  const bf16x8* bp1 = (const bf16x8*)(W2T + (size_t)(16 + l15) * HIDD + kbase);
  const bf16x8* bp2 = (const bf16x8*)(W2T + (size_t)(32 + l15) * HIDD + kbase);
  f32x4 acc0 = {0.f, 0.f, 0.f, 0.f}, acc1 = {0.f, 0.f, 0.f, 0.f}, acc2 = {0.f, 0.f, 0.f, 0.f};
#pragma unroll
  for (int kk = 0; kk < 256; kk += 32) {
    bf16x8 a = *ap; ap += 4;
    bf16x8 vb0 = *bp0; bp0 += 4;
    bf16x8 vb1 = *bp1; bp1 += 4;
    bf16x8 vb2 = *bp2; bp2 += 4;
    acc0 = __builtin_amdgcn_mfma_f32_16x16x32_bf16(a, vb0, acc0, 0, 0, 0);
    acc1 = __builtin_amdgcn_mfma_f32_16x16x32_bf16(a, vb1, acc1, 0, 0, 0);
    acc2 = __builtin_amdgcn_mfma_f32_16x16x32_bf16(a, vb2, acc2, 0, 0, 0);
  }
#pragma unroll
  for (int r = 0; r < 4; ++r) {
    red[wave][kg * 4 + r][l15] = acc0[r];
    red[wave][kg * 4 + r][16 + l15] = acc1[r];
    red[wave][kg * 4 + r][32 + l15] = acc2[r];
  }
  __syncthreads();
  if (wave == 0) {
#pragma unroll
    for (int r = 0; r < 4; ++r) {
      const int rr = kg * 4 + r;
      float v0 = red[0][rr][l15] + red[1][rr][l15] + red[2][rr][l15] + red[3][rr][l15];
      float v1 = red[0][rr][16 + l15] + red[1][rr][16 + l15] + red[2][rr][16 + l15] + red[3][rr][16 + l15];
      float v2 = red[0][rr][32 + l15] + red[1][rr][32 + l15] + red[2][rr][32 + l15] + red[3][rr][32 + l15];
      const size_t i = (size_t)blockIdx.x * 16 + rr;
      out[i * NCLS + l15] = v0 + bias2[l15];
      out[i * NCLS + 16 + l15] = v1 + bias2[16 + l15];
      if (l15 < 8) out[i * NCLS + 32 + l15] = v2 + bias2[32 + l15];
    }
  }
}

extern "C" void kernel_launch(void* const* d_in, const int* in_sizes, int n_in,
                              void* d_out, int out_size, void* d_ws, size_t ws_size,
                              hipStream_t stream) {
  const float* X = (const float*)d_in[0];
  const float* onehot = (const float*)d_in[1];
  const float* adj = (const float*)d_in[2];
  const float* W1 = (const float*)d_in[3];
  const float* b1 = (const float*)d_in[4];
  const float* W2 = (const float*)d_in[5];
  const float* b2 = (const float*)d_in[6];
  float* out = (float*)d_out;
  char* ws = (char*)d_ws;

  // workspace layout (bytes)
  unsigned char*  A8i  = (unsigned char*)(ws);                 // 67108864 (interleaved)
  float*          dinv = (float*)(ws + 67108864ull);           // 8192*4 = 32768
  unsigned char*  cur0 = (unsigned char*)(ws + 67141632ull);   // 393216
  unsigned char*  cur1 = (unsigned char*)(ws + 67534848ull);   // 393216
  unsigned short* comb = (unsigned short*)(ws + 67928064ull);  // 11010048
  unsigned short* W1T  = (unsigned short*)(ws + 78938112ull);  // 1376256
  unsigned short* W2T  = (unsigned short*)(ws + 80314368ull);  // 98304
  unsigned short* hbuf = (unsigned short*)(ws + 80412672ull);  // 16777216
  // total = 97189888 bytes

  sig_kernel<<<NN / 16, 1024, 0, stream>>>(adj, A8i, dinv);
  prep_kernel<<<2048, 256, 0, stream>>>(X, onehot, W1, W2, comb, cur0, W1T, W2T);
  hop_kernel<<<NN / 16, 512, 0, stream>>>(A8i, cur0, dinv, cur1, comb, 0);
  hop_kernel<<<NN / 16, 512, 0, stream>>>(A8i, cur1, dinv, cur0, comb, 1);
  hop_kernel<<<NN / 16, 512, 0, stream>>>(A8i, cur0, dinv, cur1, comb, 2);
  hop_kernel<<<NN / 16, 512, 0, stream>>>(A8i, cur1, dinv, cur0, comb, 3);
  gemm1_kernel<<<1024, 256, 0, stream>>>(comb, W1T, b1, hbuf);
  gemm2_kernel<<<NN / 16, 256, 0, stream>>>(hbuf, W2T, b2, out);
}

// Round 6
// 515.407 us; speedup vs baseline: 1.3598x; 1.0469x over previous
//
#include <hip/hip_runtime.h>
#include <hip/hip_bf16.h>

#define NN 8192
#define CFEAT 512
#define NCLS 40
#define NPAD 48
#define INDIM 672
#define HIDD 1024

typedef __attribute__((ext_vector_type(8))) short bf16x8;
typedef __attribute__((ext_vector_type(4))) float f32x4;
typedef __attribute__((ext_vector_type(2))) long l64x2;

// A8i holds e4m3(32 * sigmoid(adj)); d_inv applied in hop epilogue (row scaling
// commutes with the matmul). dinv[] stores 1/(32*(rowsum+1e-8)).
#define SIG_SCALE 32.0f

__device__ inline unsigned short f2b(float f) {
  union { __hip_bfloat16 b; unsigned short u; } cv;
  cv.b = __float2bfloat16(f);
  return cv.u;
}

__device__ inline unsigned char f2fp8(float f) {
  int pk = __builtin_amdgcn_cvt_pk_fp8_f32(f, 0.f, 0, false);
  return (unsigned char)(pk & 0xff);
}

// Interleaved fp8 matrix layout so hop_kernel wave-loads are CONTIGUOUS 512B:
// byte of (row r, col k), G=k>>3:
//   (r>>4)*131072 + (G>>7)*16384 + ((G>>2)&31)*512 + (G&3)*128 + (r&15)*8 + (k&7)
// Within a 16-row group this is LINEAR in G: byte = G*128 + (r&15)*8 + (k&7).
__device__ inline size_t ilv_off(int r, int G) {
  return (size_t)(r >> 4) * 131072 + (size_t)(G >> 7) * 16384 +
         (size_t)((G >> 2) & 31) * 512 + (size_t)(G & 3) * 128 + (size_t)(r & 15) * 8;
}

// ---------------------------------------------------------------------------
// sig: A8i[grp] = interleaved e4m3(32*sigmoid(adj rows 16grp..16grp+15));
//      dinv[i] = 1/(32*(rowsum_i + 1e-8)).
// One block per 16-row group, 16 waves (one row each). Per 2048-col chunk:
// sigmoid -> fp8 into LDS, then the chunk's 32768B interleaved block is
// written as fully contiguous stores. Fixed quantization scale; d_inv
// deferred to hop epilogue -> no cross-wave dependency.
// ---------------------------------------------------------------------------
__global__ __launch_bounds__(1024) void sig_kernel(const float* __restrict__ adj,
                                                   unsigned char* __restrict__ A8i,
                                                   float* __restrict__ dinv) {
  __shared__ unsigned char lds[16][2056];  // 2048 + 8B pad (breaks 8-way banks)
  const int t = threadIdx.x;
  const int wave = t >> 6;   // row within group
  const int lane = t & 63;
  const size_t grp = blockIdx.x;  // 0..511
  const size_t row = grp * 16 + wave;
  const float4* src = (const float4*)(adj + row * NN);
  unsigned char* dst = A8i + grp * 131072;
  float sum = 0.f;
  for (int m = 0; m < 4; ++m) {
#pragma unroll
    for (int it = 0; it < 8; ++it) {
      const int idx = it * 64 + lane;  // float4 index within chunk: 0..511
      float4 x = src[m * 512 + idx];
      float s0 = __builtin_amdgcn_rcpf(1.f + __expf(-x.x));
      float s1 = __builtin_amdgcn_rcpf(1.f + __expf(-x.y));
      float s2 = __builtin_amdgcn_rcpf(1.f + __expf(-x.z));
      float s3 = __builtin_amdgcn_rcpf(1.f + __expf(-x.w));
      sum += (s0 + s1) + (s2 + s3);
      int lo = __builtin_amdgcn_cvt_pk_fp8_f32(s0 * SIG_SCALE, s1 * SIG_SCALE, 0, false);
      int pk = __builtin_amdgcn_cvt_pk_fp8_f32(s2 * SIG_SCALE, s3 * SIG_SCALE, lo, true);
      *(unsigned int*)&lds[wave][idx * 4] = (unsigned int)pk;
    }
    __syncthreads();
#pragma unroll
    for (int pass = 0; pass < 2; ++pass) {
      const int v = pass * 1024 + t;  // 0..2047
      const int g = v >> 3, q = v & 7;
      l64x2 val;
      val[0] = *(const long*)&lds[2 * q][g * 8];
      val[1] = *(const long*)&lds[2 * q + 1][g * 8];
      *(l64x2*)(dst + (size_t)m * 32768 + (size_t)v * 16) = val;
    }
    __syncthreads();
  }
#pragma unroll
  for (int s = 1; s < 64; s <<= 1) sum += __shfl_xor(sum, s);
  if (lane == 0) dinv[row] = 1.f / (SIG_SCALE * (sum + 1e-8f));
}

// ---------------------------------------------------------------------------
// prep: X -> combined[:, :512] bf16 ; onehot -> curT0 [48 x 8192] fp8
// (interleaved layout); W1 -> W1T bf16 ; W2 -> W2T bf16. pad rows of curT/W2T
// stay poisoned (finite or NaN is fine: per-lane isolated + masked downstream).
// ---------------------------------------------------------------------------
__global__ __launch_bounds__(256) void prep_kernel(const float* __restrict__ X,
                                                   const float* __restrict__ onehot,
                                                   const float* __restrict__ W1,
                                                   const float* __restrict__ W2,
                                                   unsigned short* __restrict__ comb,
                                                   unsigned char* __restrict__ curT0,
                                                   unsigned short* __restrict__ W1T,
                                                   unsigned short* __restrict__ W2T) {
  const int NX = NN * CFEAT;
  const int NO = NCLS * NN;
  const int NW1 = INDIM * HIDD;
  const int NW2 = HIDD * NCLS;
  const int total = NX + NO + NW1 + NW2;
  for (int idx = blockIdx.x * 256 + threadIdx.x; idx < total; idx += gridDim.x * 256) {
    if (idx < NX) {
      int i = idx >> 9, c = idx & 511;
      comb[(size_t)i * INDIM + c] = f2b(X[idx]);
    } else if (idx < NX + NO) {
      int t = idx - NX;
      int c = t >> 13, i = t & 8191;
      curT0[ilv_off(c, i >> 3) + (i & 7)] = f2fp8(onehot[(size_t)i * NCLS + c]);
    } else if (idx < NX + NO + NW1) {
      int t = idx - NX - NO;
      int k = t >> 10, n = t & 1023;
      W1T[(size_t)n * INDIM + k] = f2b(W1[t]);
    } else {
      int t = idx - NX - NO - NW1;
      int k = t / NCLS, c = t - k * NCLS;
      W2T[(size_t)c * HIDD + k] = f2b(W2[t]);
    }
  }
}

// ---------------------------------------------------------------------------
// hop: next = softmax(dinv[i] * (A8 @ curT^T)) ; fp8 MFMA 16x16x32.
// v2: block = 32 output rows (2 A-groups), 16 waves K-split (512 each).
// Each block reads curT exactly ONCE (B logical traffic halved vs 16-row
// blocks). All loads contiguous 512B. Epilogue: 8 waves x 4 kg = one row
// each, 16-slot LDS reduce + d_inv + softmax.
// ---------------------------------------------------------------------------
__global__ __launch_bounds__(1024) void hop_kernel(const unsigned char* __restrict__ A8,
                                                   const unsigned char* __restrict__ curT,
                                                   const float* __restrict__ dinv,
                                                   unsigned char* __restrict__ nextT,
                                                   unsigned short* __restrict__ comb,
                                                   int hop) {
  __shared__ float red[16][32][50];  // 50: pad so kg-stride (4*50) spreads banks
  const int lane = threadIdx.x & 63;
  const int wave = threadIdx.x >> 6;  // 0..15, K-slice of 512
  const int l15 = lane & 15;
  const int kg = lane >> 4;
  const long* ap0 = (const long*)(A8 + (size_t)blockIdx.x * 262144 + (size_t)wave * 8192) + lane;
  const long* ap1 = (const long*)(A8 + (size_t)blockIdx.x * 262144 + 131072 + (size_t)wave * 8192) + lane;
  const long* bp0 = (const long*)(curT +          (size_t)wave * 8192) + lane;
  const long* bp1 = (const long*)(curT + 131072 + (size_t)wave * 8192) + lane;
  const long* bp2 = (const long*)(curT + 262144 + (size_t)wave * 8192) + lane;
  f32x4 acc[2][3] = {};
#pragma unroll 4
  for (int t = 0; t < 16; ++t) {
    long a0 = ap0[t * 64];
    long a1 = ap1[t * 64];
    long b0 = bp0[t * 64];
    long b1 = bp1[t * 64];
    long b2 = bp2[t * 64];
    acc[0][0] = __builtin_amdgcn_mfma_f32_16x16x32_fp8_fp8(a0, b0, acc[0][0], 0, 0, 0);
    acc[0][1] = __builtin_amdgcn_mfma_f32_16x16x32_fp8_fp8(a0, b1, acc[0][1], 0, 0, 0);
    acc[0][2] = __builtin_amdgcn_mfma_f32_16x16x32_fp8_fp8(a0, b2, acc[0][2], 0, 0, 0);
    acc[1][0] = __builtin_amdgcn_mfma_f32_16x16x32_fp8_fp8(a1, b0, acc[1][0], 0, 0, 0);
    acc[1][1] = __builtin_amdgcn_mfma_f32_16x16x32_fp8_fp8(a1, b1, acc[1][1], 0, 0, 0);
    acc[1][2] = __builtin_amdgcn_mfma_f32_16x16x32_fp8_fp8(a1, b2, acc[1][2], 0, 0, 0);
  }
#pragma unroll
  for (int aidx = 0; aidx < 2; ++aidx)
#pragma unroll
    for (int p = 0; p < 3; ++p)
#pragma unroll
      for (int r = 0; r < 4; ++r)
        red[wave][aidx * 16 + kg * 4 + r][p * 16 + l15] = acc[aidx][p][r];
  __syncthreads();
  if (wave < 8) {
    const int rr = wave * 4 + kg;  // one of 32 rows per (wave,kg)
    const size_t i = (size_t)blockIdx.x * 32 + rr;
    const float dv = dinv[i];      // broadcast (same for all l15 lanes)
    float v0 = 0.f, v1 = 0.f, v2 = 0.f;
#pragma unroll
    for (int w = 0; w < 16; ++w) {
      v0 += red[w][rr][l15];
      v1 += red[w][rr][16 + l15];
      v2 += red[w][rr][32 + l15];
    }
    v0 *= dv; v1 *= dv; v2 *= dv;
    const bool ok2 = l15 < 8;  // cols 32..39 valid, 40..47 are padding
    float m = fmaxf(v0, v1);
    if (ok2) m = fmaxf(m, v2);
#pragma unroll
    for (int s = 1; s < 16; s <<= 1) m = fmaxf(m, __shfl_xor(m, s));
    float e0 = __expf(v0 - m);
    float e1 = __expf(v1 - m);
    float e2 = ok2 ? __expf(v2 - m) : 0.f;
    float ssum = e0 + e1 + e2;
#pragma unroll
    for (int s = 1; s < 16; s <<= 1) ssum += __shfl_xor(ssum, s);
    const float inv = 1.f / ssum;
    const float p0 = e0 * inv;
    const float p1 = e1 * inv;
    // interleaved writes into nextT (row = class c, col = node i)
    const int G = (int)(i >> 3);
    const size_t joff = (size_t)(G >> 7) * 16384 + (size_t)((G >> 2) & 31) * 512 +
                        (size_t)(G & 3) * 128 + (i & 7);
    nextT[joff + (size_t)l15 * 8] = f2fp8(p0);
    nextT[131072 + joff + (size_t)l15 * 8] = f2fp8(p1);
    const size_t cbase = i * INDIM + CFEAT + (size_t)hop * NCLS;
    comb[cbase + l15] = f2b(p0);
    comb[cbase + 16 + l15] = f2b(p1);
    if (ok2) {
      const float p2 = e2 * inv;
      nextT[262144 + joff + (size_t)l15 * 8] = f2fp8(p2);
      comb[cbase + 32 + l15] = f2b(p2);
    }
  }
}

// ---------------------------------------------------------------------------
// GEMM1: h = relu(combined @ W1 + b1), bf16 out.
// v2: tile 128(M) x 128(N), 4 waves (each 32Mx128N, acc[2][8]): B-rows read
// once per 128 output rows instead of per 64 -> fewer L1 transactions/FLOP.
// ---------------------------------------------------------------------------
__global__ __launch_bounds__(256) void gemm1_kernel(const unsigned short* __restrict__ comb,
                                                    const unsigned short* __restrict__ W1T,
                                                    const float* __restrict__ bias1,
                                                    unsigned short* __restrict__ h) {
  const int lane = threadIdx.x & 63;
  const int wave = threadIdx.x >> 6;
  const int l15 = lane & 15;
  const int kg = lane >> 4;
  const int bm = blockIdx.x & 63;
  const int bn = blockIdx.x >> 6;
  const size_t arow0 = (size_t)bm * 128 + wave * 32 + l15;
  const bf16x8* ap0 = (const bf16x8*)(comb + arow0 * INDIM + (size_t)kg * 8);
  const bf16x8* ap1 = (const bf16x8*)(comb + (arow0 + 16) * INDIM + (size_t)kg * 8);
  const bf16x8* bp[8];
#pragma unroll
  for (int tt = 0; tt < 8; ++tt)
    bp[tt] = (const bf16x8*)(W1T + (size_t)(bn * 128 + tt * 16 + l15) * INDIM + (size_t)kg * 8);
  f32x4 acc[2][8] = {};
#pragma unroll 3
  for (int kk = 0; kk < INDIM; kk += 32) {
    bf16x8 a0 = *ap0; ap0 += 4;
    bf16x8 a1 = *ap1; ap1 += 4;
#pragma unroll
    for (int tt = 0; tt < 8; ++tt) {
      bf16x8 b = *bp[tt]; bp[tt] += 4;
      acc[0][tt] = __builtin_amdgcn_mfma_f32_16x16x32_bf16(a0, b, acc[0][tt], 0, 0, 0);
      acc[1][tt] = __builtin_amdgcn_mfma_f32_16x16x32_bf16(a1, b, acc[1][tt], 0, 0, 0);
    }
  }
#pragma unroll
  for (int tt = 0; tt < 8; ++tt) {
    const int n = bn * 128 + tt * 16 + l15;
    const float bv = bias1[n];
#pragma unroll
    for (int aidx = 0; aidx < 2; ++aidx) {
#pragma unroll
      for (int r = 0; r < 4; ++r) {
        const size_t i = (size_t)bm * 128 + wave * 32 + aidx * 16 + kg * 4 + r;
        float v = acc[aidx][tt][r] + bv;
        h[i * HIDD + n] = f2b(v > 0.f ? v : 0.f);
      }
    }
  }
}

// ---------------------------------------------------------------------------
// GEMM2: out = h @ W2 + b2 (fp32 out). bf16 MFMA, 4-wave K-split + LDS reduce.
// ---------------------------------------------------------------------------
__global__ __launch_bounds__(256) void gemm2_kernel(const unsigned short* __restrict__ h,
                                                    const unsigned short* __restrict__ W2T,
                                                    const float* __restrict__ bias2,
                                                    float* __restrict__ out) {
  __shared__ float red[4][16][NPAD];
  const int lane = threadIdx.x & 63;
  const int wave = threadIdx.x >> 6;
  const int l15 = lane & 15;
  const int kg = lane >> 4;
  const size_t arow = (size_t)blockIdx.x * 16 + l15;
  const size_t kbase = (size_t)wave * 256 + (size_t)kg * 8;
  const bf16x8* ap = (const bf16x8*)(h + arow * HIDD + kbase);
  const bf16x8* bp0 = (const bf16x8*)(W2T + (size_t)l15 * HIDD + kbase);
  const bf16x8* bp1 = (const bf16x8*)(W2T + (size_t)(16 + l15) * HIDD + kbase);
  const bf16x8* bp2 = (const bf16x8*)(W2T + (size_t)(32 + l15) * HIDD + kbase);
  f32x4 acc0 = {0.f, 0.f, 0.f, 0.f}, acc1 = {0.f, 0.f, 0.f, 0.f}, acc2 = {0.f, 0.f, 0.f, 0.f};
#pragma unroll
  for (int kk = 0; kk < 256; kk += 32) {
    bf16x8 a = *ap; ap += 4;
    bf16x8 vb0 = *bp0; bp0 += 4;
    bf16x8 vb1 = *bp1; bp1 += 4;
    bf16x8 vb2 = *bp2; bp2 += 4;
    acc0 = __builtin_amdgcn_mfma_f32_16x16x32_bf16(a, vb0, acc0, 0, 0, 0);
    acc1 = __builtin_amdgcn_mfma_f32_16x16x32_bf16(a, vb1, acc1, 0, 0, 0);
    acc2 = __builtin_amdgcn_mfma_f32_16x16x32_bf16(a, vb2, acc2, 0, 0, 0);
  }
#pragma unroll
  for (int r = 0; r < 4; ++r) {
    red[wave][kg * 4 + r][l15] = acc0[r];
    red[wave][kg * 4 + r][16 + l15] = acc1[r];
    red[wave][kg * 4 + r][32 + l15] = acc2[r];
  }
  __syncthreads();
  if (wave == 0) {
#pragma unroll
    for (int r = 0; r < 4; ++r) {
      const int rr = kg * 4 + r;
      float v0 = red[0][rr][l15] + red[1][rr][l15] + red[2][rr][l15] + red[3][rr][l15];
      float v1 = red[0][rr][16 + l15] + red[1][rr][16 + l15] + red[2][rr][16 + l15] + red[3][rr][16 + l15];
      float v2 = red[0][rr][32 + l15] + red[1][rr][32 + l15] + red[2][rr][32 + l15] + red[3][rr][32 + l15];
      const size_t i = (size_t)blockIdx.x * 16 + rr;
      out[i * NCLS + l15] = v0 + bias2[l15];
      out[i * NCLS + 16 + l15] = v1 + bias2[16 + l15];
      if (l15 < 8) out[i * NCLS + 32 + l15] = v2 + bias2[32 + l15];
    }
  }
}

extern "C" void kernel_launch(void* const* d_in, const int* in_sizes, int n_in,
                              void* d_out, int out_size, void* d_ws, size_t ws_size,
                              hipStream_t stream) {
  const float* X = (const float*)d_in[0];
  const float* onehot = (const float*)d_in[1];
  const float* adj = (const float*)d_in[2];
  const float* W1 = (const float*)d_in[3];
  const float* b1 = (const float*)d_in[4];
  const float* W2 = (const float*)d_in[5];
  const float* b2 = (const float*)d_in[6];
  float* out = (float*)d_out;
  char* ws = (char*)d_ws;

  // workspace layout (bytes)
  unsigned char*  A8i  = (unsigned char*)(ws);                 // 67108864 (interleaved)
  float*          dinv = (float*)(ws + 67108864ull);           // 8192*4 = 32768
  unsigned char*  cur0 = (unsigned char*)(ws + 67141632ull);   // 393216
  unsigned char*  cur1 = (unsigned char*)(ws + 67534848ull);   // 393216
  unsigned short* comb = (unsigned short*)(ws + 67928064ull);  // 11010048
  unsigned short* W1T  = (unsigned short*)(ws + 78938112ull);  // 1376256
  unsigned short* W2T  = (unsigned short*)(ws + 80314368ull);  // 98304
  unsigned short* hbuf = (unsigned short*)(ws + 80412672ull);  // 16777216
  // total = 97189888 bytes

  sig_kernel<<<NN / 16, 1024, 0, stream>>>(adj, A8i, dinv);
  prep_kernel<<<2048, 256, 0, stream>>>(X, onehot, W1, W2, comb, cur0, W1T, W2T);
  hop_kernel<<<NN / 32, 1024, 0, stream>>>(A8i, cur0, dinv, cur1, comb, 0);
  hop_kernel<<<NN / 32, 1024, 0, stream>>>(A8i, cur1, dinv, cur0, comb, 1);
  hop_kernel<<<NN / 32, 1024, 0, stream>>>(A8i, cur0, dinv, cur1, comb, 2);
  hop_kernel<<<NN / 32, 1024, 0, stream>>>(A8i, cur1, dinv, cur0, comb, 3);
  gemm1_kernel<<<512, 256, 0, stream>>>(comb, W1T, b1, hbuf);
  gemm2_kernel<<<NN / 16, 256, 0, stream>>>(hbuf, W2T, b2, out);
}